// Round 1
// 7960.098 us; speedup vs baseline: 1.0944x; 1.0944x over previous
//
#include <hip/hip_runtime.h>

typedef __bf16 bf16;
typedef __bf16 v8bf __attribute__((ext_vector_type(8)));
typedef __bf16 v4bf __attribute__((ext_vector_type(4)));
typedef float  v4f  __attribute__((ext_vector_type(4)));

// B=128, T=256, D=H=V=1024, S=128.
//
// Step structure (3 launches/step):
//   kFused1: scores via exp-form tanh + softmax + unnormalized context halves
//            (2 wgs per b) || output softmax for step-1 (128 wgs)
//   kXGru:   [c0|c1|y] @ [gru_w_ih | rnn_w_ih_c | rnn_w_hh]^T (gate-interleaved),
//            K-split across wave groups, LDS-accumulated, fused GRU pointwise
//   kGemmPS: s_new @ [rnn_w_ih_s; w_s_a; gru_w_hh]^T (K-split partials)

static __device__ __forceinline__ float fast_tanh(float x) {
  x = fminf(fmaxf(x, -10.f), 10.f);
  float e = __expf(2.f * x);
  return (e - 1.f) * __builtin_amdgcn_rcpf(e + 1.f);
}
static __device__ __forceinline__ float fast_sigmoid(float x) {
  return __builtin_amdgcn_rcpf(1.f + __expf(-x));
}

// MFMA-fragment packing (HW-verified layout): element (r,k) of X[R][32*nksb] at
//   off = (((r>>4)*nksb + (k>>5))*64 + ((k>>3)&3)*16 + (r&15))*8 + (k&7)
static __device__ __forceinline__ size_t packOffN(int r, int k, int nksb) {
  return ((size_t)((r >> 4) * nksb + (k >> 5)) * 64 + ((k >> 3) & 3) * 16 + (r & 15)) * 8 + (k & 7);
}

// No-LDS GEMM tile core: 64x64 tile, 256 thr (4 waves, 2x2 of 32x32).
template<int NKS, int NKSB>
static __device__ __forceinline__ void gemmTile(const bf16* __restrict__ Ap,
                                                const bf16* __restrict__ Bp,
                                                int m0, int n0, int ks0,
                                                v4f acc[2][2]) {
  const int lane = threadIdx.x & 63;
  const int w = threadIdx.x >> 6;
  const int wr = w >> 1, wc = w & 1;
  const bf16* a0p = Ap + (((size_t)((m0 >> 4) + wr * 2) * NKSB + ks0) * 64 + lane) * 8;
  const bf16* b0p = Bp + (((size_t)((n0 >> 4) + wc * 2) * NKSB + ks0) * 64 + lane) * 8;
#pragma unroll 8
  for (int ks = 0; ks < NKS; ks++) {
    v8bf a0 = *(const v8bf*)(a0p);
    v8bf a1 = *(const v8bf*)(a0p + NKSB * 512);
    v8bf b0 = *(const v8bf*)(b0p);
    v8bf b1 = *(const v8bf*)(b0p + NKSB * 512);
    a0p += 512; b0p += 512;
    acc[0][0] = __builtin_amdgcn_mfma_f32_16x16x32_bf16(a0, b0, acc[0][0], 0, 0, 0);
    acc[0][1] = __builtin_amdgcn_mfma_f32_16x16x32_bf16(a0, b1, acc[0][1], 0, 0, 0);
    acc[1][0] = __builtin_amdgcn_mfma_f32_16x16x32_bf16(a1, b0, acc[1][0], 0, 0, 0);
    acc[1][1] = __builtin_amdgcn_mfma_f32_16x16x32_bf16(a1, b1, acc[1][1], 0, 0, 0);
  }
}

// C/D layout (HW-verified): col = lane&15, row = (lane>>4)*4 + i
static __device__ __forceinline__ void storeTileF32(float* __restrict__ C, int ldc,
                                                    int m0, int n0, v4f acc[2][2]) {
  const int lane = threadIdx.x & 63, w = threadIdx.x >> 6;
  const int wr = w >> 1, wc = w & 1;
  const int mB = m0 + wr * 32 + (lane >> 4) * 4;
  const int nB = n0 + wc * 32 + (lane & 15);
#pragma unroll
  for (int mf = 0; mf < 2; mf++)
#pragma unroll
    for (int nf = 0; nf < 2; nf++)
#pragma unroll
      for (int i = 0; i < 4; i++)
        C[(size_t)(mB + mf * 16 + i) * ldc + nB + nf * 16] = acc[mf][nf][i];
}

// ---------------------------------------------------------------------------
// Setup kernels
// ---------------------------------------------------------------------------
// f32 [r][k] (ld) -> fragment-packed bf16 at row offset r0, nksb=32 layouts.
__global__ __launch_bounds__(256) void kPackG(const float* __restrict__ src, int ld,
                                              bf16* __restrict__ dst, int nTh, int r0) {
  int th = blockIdx.x * 256 + threadIdx.x;
  if (th >= nTh) return;
  int rb = th >> 11, ks = (th >> 6) & 31, l = th & 63;
  int r = rb * 16 + (l & 15);
  int k = ks * 32 + ((l >> 4) & 3) * 8;
  const float* s = src + (size_t)r * ld + k;
  v4f v0 = *(const v4f*)(s);
  v4f v1 = *(const v4f*)(s + 4);
  v8bf o;
#pragma unroll
  for (int e = 0; e < 4; e++) { o[e] = (bf16)v0[e]; o[4 + e] = (bf16)v1[e]; }
  *(v8bf*)(dst + packOffN(r0 + r, k, 32)) = o;
}

// Gate-interleaved combined weight pack: rows n = Jb*64 + g*16 + jo, K=2048.
//   g<3 : gru_w_ih[g*1024 + j][k]          (k in [0,2048))
//   g==3: k<1024 -> rnn_w_ih[j][k], else rnn_w_hh[j][k-1024]
__global__ __launch_bounds__(256) void kPackW(const float* __restrict__ gih,
                                              const float* __restrict__ rih,
                                              const float* __restrict__ rhh,
                                              bf16* __restrict__ dst) {
  const int th = blockIdx.x * 256 + threadIdx.x;   // 1,048,576 total
  const int rb = th >> 12;
  const int ks = (th >> 6) & 63;
  const int l = th & 63;
  const int n = rb * 16 + (l & 15);
  const int k = ks * 32 + ((l >> 4) & 3) * 8;
  const int g = (n >> 4) & 3;
  const int j = ((n >> 6) << 4) | (n & 15);
  const float* s;
  if (g < 3)            s = gih + (size_t)(g * 1024 + j) * 2048 + k;
  else if (k < 1024)    s = rih + (size_t)j * 2048 + k;
  else                  s = rhh + (size_t)j * 1024 + (k - 1024);
  v4f v0 = *(const v4f*)(s);
  v4f v1 = *(const v4f*)(s + 4);
  v8bf o;
#pragma unroll
  for (int e = 0; e < 4; e++) { o[e] = (bf16)v0[e]; o[4 + e] = (bf16)v1[e]; }
  *(v8bf*)(dst + (size_t)th * 8) = o;
}

// plain f32 -> bf16 linear cast (x4)
__global__ __launch_bounds__(256) void kCast4(const float* __restrict__ src,
                                              bf16* __restrict__ dst, int n4) {
  int i = blockIdx.x * 256 + threadIdx.x;
  if (i < n4) {
    v4f v = ((const v4f*)src)[i];
    ((v4bf*)dst)[i] = __builtin_convertvector(v, v4bf);
  }
}

// bias sum, Wsum = sum(w_a), zero the y-region of xcat (ks 64..95, nksb=96)
__global__ __launch_bounds__(256) void kPrep(const float* __restrict__ rnn_b_ih,
                                             const float* __restrict__ rnn_b_hh,
                                             const float* __restrict__ w_a,
                                             float* __restrict__ bsum,
                                             float* __restrict__ wsum,
                                             bf16* __restrict__ xcatp) {
  __shared__ float sred[4];
  if (blockIdx.x < 64) {
    int th = blockIdx.x * 256 + threadIdx.x;
    int rb = th >> 11, ks = 64 + ((th >> 6) & 31), l = th & 63;
    v8bf z = {};
    *(v8bf*)(xcatp + ((size_t)(rb * 96 + ks) * 64 + l) * 8) = z;
  } else {
    int t = threadIdx.x;
    v4f a = *(const v4f*)(rnn_b_ih + t * 4);
    v4f c = *(const v4f*)(rnn_b_hh + t * 4);
    *(v4f*)(bsum + t * 4) = a + c;
    float zz = w_a[t] + w_a[256 + t] + w_a[512 + t] + w_a[768 + t];
#pragma unroll
    for (int off = 32; off; off >>= 1) zz += __shfl_down(zz, off, 64);
    if ((t & 63) == 0) sred[t >> 6] = zz;
    __syncthreads();
    if (t == 0) wsum[0] = sred[0] + sred[1] + sred[2] + sred[3];
  }
}

// E = exp(2 * (h @ w_h_a^T)) -> bf16 linear (M=32768, N=1024)
__global__ __launch_bounds__(256) void kGemmE(const bf16* __restrict__ Ap,
                                              const bf16* __restrict__ Bp,
                                              bf16* __restrict__ C) {
  const int nt = blockIdx.x & 15, mt = blockIdx.x >> 4;
  v4f acc[2][2] = {};
  gemmTile<32, 32>(Ap, Bp, mt * 64, nt * 64, 0, acc);
  const int lane = threadIdx.x & 63, w = threadIdx.x >> 6;
  const int wr = w >> 1, wc = w & 1;
  const int mB = mt * 64 + wr * 32 + (lane >> 4) * 4;
  const int nB = nt * 64 + wc * 32 + (lane & 15);
#pragma unroll
  for (int mf = 0; mf < 2; mf++)
#pragma unroll
    for (int nf = 0; nf < 2; nf++)
#pragma unroll
      for (int i = 0; i < 4; i++)
        C[(size_t)(mB + mf * 16 + i) * 1024 + nB + nf * 16] = (bf16)__expf(2.f * acc[mf][nf][i]);
}

// s0 = tanh(h0 @ w_init_s^T + b_init_s) -> packed f32 + packed bf16 (M=128)
__global__ __launch_bounds__(256) void kGemmS0(const bf16* __restrict__ Ap,
                                               const bf16* __restrict__ Bp,
                                               const float* __restrict__ bias,
                                               float* __restrict__ sF, bf16* __restrict__ sB) {
  const int nt = blockIdx.x & 15, mt = blockIdx.x >> 4;
  v4f acc[2][2] = {};
  gemmTile<32, 32>(Ap, Bp, mt * 64, nt * 64, 0, acc);
  const int lane = threadIdx.x & 63, w = threadIdx.x >> 6;
  const int wr = w >> 1, wc = w & 1;
  const int mB = mt * 64 + wr * 32 + (lane >> 4) * 4;
  const int nB = nt * 64 + wc * 32 + (lane & 15);
#pragma unroll
  for (int mf = 0; mf < 2; mf++)
#pragma unroll
    for (int nf = 0; nf < 2; nf++) {
      const int n = nB + nf * 16;
      float bv = bias[n];
#pragma unroll
      for (int i = 0; i < 4; i++) {
        const int m = mB + mf * 16 + i;
        float v = fast_tanh(acc[mf][nf][i] + bv);
        size_t pi = packOffN(m, n, 32);
        sF[pi] = v;
        sB[pi] = (bf16)v;
      }
    }
}

// [pres|sa|gh] partials = s @ WP5^T, K-split x2 (grid 320)
__global__ __launch_bounds__(256) void kGemmPS(const bf16* __restrict__ Ap,
                                               const bf16* __restrict__ Bp,
                                               float* __restrict__ PS0, float* __restrict__ PS1) {
  const int t = blockIdx.x;
  const int kh = t & 1, mh = (t >> 1) & 1, nt = t >> 2;
  v4f acc[2][2] = {};
  gemmTile<16, 32>(Ap, Bp, mh * 64, nt * 64, kh * 16, acc);
  storeTileF32(kh ? PS1 : PS0, 5120, mh * 64, nt * 64, acc);
}

// ---------------------------------------------------------------------------
// Per-step kernels
// ---------------------------------------------------------------------------

// Output softmax for `step`: pre = PS(pres) + gcpR(prec+prey) + bsum;
// y = softmax(tanh(pre)) -> out[:,step,:] and y-region of xcat (packed).
static __device__ __forceinline__ void outPhase256(
    int b, int step,
    const float* __restrict__ PS0, const float* __restrict__ PS1,
    const float* __restrict__ gcpR, const float* __restrict__ bsum,
    float* __restrict__ out, bf16* __restrict__ xcatp, float* smred) {
  const int tid = threadIdx.x, lane = tid & 63, w = tid >> 6;
  const int v0 = tid * 4;
  const size_t o5 = (size_t)b * 5120 + v0;
  const size_t oR = (size_t)b * 1024 + v0;
  v4f pre = *(const v4f*)(PS0 + o5);
  pre += *(const v4f*)(PS1 + o5);
  pre += *(const v4f*)(gcpR + oR);
  pre += *(const v4f*)(bsum + v0);
  float ee[4]; float psum = 0.f;
#pragma unroll
  for (int i = 0; i < 4; i++) { ee[i] = __expf(fast_tanh(pre[i])); psum += ee[i]; }
#pragma unroll
  for (int off = 32; off; off >>= 1) psum += __shfl_down(psum, off, 64);
  if (lane == 0) smred[w] = psum;
  __syncthreads();
  const float rden = __builtin_amdgcn_rcpf(smred[0] + smred[1] + smred[2] + smred[3]);
  v4f y4;
#pragma unroll
  for (int i = 0; i < 4; i++) y4[i] = ee[i] * rden;
  *(v4f*)(out + ((size_t)b * 128 + step) * 1024 + v0) = y4;
  v4bf yb;
#pragma unroll
  for (int i = 0; i < 4; i++) yb[i] = (bf16)y4[i];
  *(v4bf*)(xcatp + packOffN(b, 2048 + v0, 96)) = yb;
}

// wg<256: scores for (b=wg>>1, half=wg&1) via score = Wsum - 2*sum w/(1+E*F),
//         then exp(score), partial Z, and UNNORMALIZED context half -> xcat.
// wg>=256 (128 wgs): output softmax for step-1 (skipped when step==0).
__global__ __launch_bounds__(256) void kFused1(
    const float* __restrict__ PS0, const float* __restrict__ PS1,
    const float* __restrict__ b_s_a, const float* __restrict__ w_a,
    const float* __restrict__ wsum,
    const bf16* __restrict__ Eb, const bf16* __restrict__ hb,
    const float* __restrict__ gcpR, const float* __restrict__ bsum,
    float* __restrict__ Zpart, float* __restrict__ out,
    bf16* __restrict__ xcatp, int step) {
  __shared__ float sF[1024];
  __shared__ float sP[128];
  __shared__ float sred[4];
  const int tid = threadIdx.x, lane = tid & 63, w = tid >> 6;
  if (blockIdx.x >= 256) {
    if (step == 0) return;
    outPhase256(blockIdx.x - 256, step - 1, PS0, PS1, gcpR, bsum, out, xcatp, sred);
    return;
  }
  const int b = blockIdx.x >> 1, half = blockIdx.x & 1;
  {
    const int i = tid * 4;
    const size_t o = (size_t)b * 5120 + 1024 + i;
    v4f sa0 = *(const v4f*)(PS0 + o);
    v4f sa1 = *(const v4f*)(PS1 + o);
    v4f bsa = *(const v4f*)(b_s_a + i);
    v4f f;
#pragma unroll
    for (int e = 0; e < 4; e++) f[e] = __expf(2.f * (sa0[e] + sa1[e] + bsa[e]));
    *(v4f*)&sF[i] = f;
  }
  __syncthreads();
  float Fr[16], wv[16];
  const int h0 = lane * 16;
#pragma unroll
  for (int jj = 0; jj < 4; jj++) {
    *(v4f*)&Fr[jj * 4] = *(const v4f*)&sF[h0 + jj * 4];
    *(v4f*)&wv[jj * 4] = *(const v4f*)(w_a + h0 + jj * 4);
  }
  const float Wsum = wsum[0];
  const bf16* Erow = Eb + ((size_t)b * 256 + half * 128 + w * 32) * 1024 + h0;
  for (int ti = 0; ti < 32; ti++) {
    v8bf ea = *(const v8bf*)(Erow);
    v8bf eb2 = *(const v8bf*)(Erow + 8);
    Erow += 1024;
    float acc = 0.f;
    // paired reciprocal: w0/d0 + w1/d1 = (w0*d1 + w1*d0) / (d0*d1)
#pragma unroll
    for (int jp = 0; jp < 4; jp++) {
      float d0 = __builtin_fmaf((float)ea[2 * jp],     Fr[2 * jp],     1.f);
      float d1 = __builtin_fmaf((float)ea[2 * jp + 1], Fr[2 * jp + 1], 1.f);
      float nu = wv[2 * jp] * d1;
      nu = __builtin_fmaf(wv[2 * jp + 1], d0, nu);
      acc = __builtin_fmaf(nu, __builtin_amdgcn_rcpf(d0 * d1), acc);
      float t0 = __builtin_fmaf((float)eb2[2 * jp],     Fr[8 + 2 * jp],     1.f);
      float t1 = __builtin_fmaf((float)eb2[2 * jp + 1], Fr[8 + 2 * jp + 1], 1.f);
      float nu2 = wv[8 + 2 * jp] * t1;
      nu2 = __builtin_fmaf(wv[8 + 2 * jp + 1], t0, nu2);
      acc = __builtin_fmaf(nu2, __builtin_amdgcn_rcpf(t0 * t1), acc);
    }
#pragma unroll
    for (int off = 32; off; off >>= 1) acc += __shfl_down(acc, off, 64);
    if (lane == 0) sP[w * 32 + ti] = __expf(Wsum - 2.f * acc);
  }
  __syncthreads();
  float zv = (tid < 128) ? sP[tid] : 0.f;
#pragma unroll
  for (int off = 32; off; off >>= 1) zv += __shfl_down(zv, off, 64);
  if (lane == 0) sred[w] = zv;
  __syncthreads();
  if (tid == 0) Zpart[2 * b + half] = sred[0] + sred[1] + sred[2] + sred[3];
  // unnormalized context half -> xcat columns [half*1024, half*1024+1024)
  const int d0 = tid * 4;
  const bf16* hp = hb + (size_t)b * 262144 + (size_t)half * 131072 + d0;
  v4f cacc = {};
#pragma unroll 8
  for (int t = 0; t < 128; t++) {
    v4bf h4 = *(const v4bf*)hp;
    hp += 1024;
    cacc += sP[t] * __builtin_convertvector(h4, v4f);
  }
  v4bf cb;
#pragma unroll
  for (int e = 0; e < 4; e++) cb[e] = (bf16)cacc[e];
  *(v4bf*)(xcatp + packOffN(b, half * 1024 + d0, 96)) = cb;
}

// Combined GEMM + fused GRU. Grid 128 (mh x Jb), 768 thr = 12 waves:
// wave w: kg = w>>2 (0,1 = context halves vs Wc; 2 = y vs Wy), q = quadrant.
// 64x64 gate tile per wg accumulated in LDS, then GRU pointwise + gcpR.
__global__ __launch_bounds__(768) void kXGru(
    const bf16* __restrict__ xcatp, const bf16* __restrict__ Wbigp,
    const float* __restrict__ PS0, const float* __restrict__ PS1,
    const float* __restrict__ gru_b_ih, const float* __restrict__ gru_b_hh,
    const float* __restrict__ Zpart,
    float* __restrict__ s_f32p, bf16* __restrict__ s_b16p,
    float* __restrict__ gcpR) {
  __shared__ float tl[3][64][68];
  const int tid = threadIdx.x, lane = tid & 63, w = tid >> 6;
  const int mh = blockIdx.x & 1, Jb = blockIdx.x >> 1;
  const int kg = w >> 2, q = w & 3;
  const int rb0 = mh * 4 + (q >> 1) * 2;
  const int nb0 = Jb * 4 + (q & 1) * 2;
  const int ksA = kg * 32;
  const int ksB = (kg == 2) ? 32 : 0;     // c halves share the same Wc columns
  v4f acc[2][2] = {};
  const bf16* a0p = xcatp + (((size_t)rb0 * 96 + ksA) * 64 + lane) * 8;
  const bf16* b0p = Wbigp + (((size_t)nb0 * 64 + ksB) * 64 + lane) * 8;
#pragma unroll 8
  for (int ks = 0; ks < 32; ks++) {
    v8bf a0 = *(const v8bf*)(a0p);
    v8bf a1 = *(const v8bf*)(a0p + 96 * 512);
    v8bf b0 = *(const v8bf*)(b0p);
    v8bf b1 = *(const v8bf*)(b0p + 64 * 512);
    a0p += 512; b0p += 512;
    acc[0][0] = __builtin_amdgcn_mfma_f32_16x16x32_bf16(a0, b0, acc[0][0], 0, 0, 0);
    acc[0][1] = __builtin_amdgcn_mfma_f32_16x16x32_bf16(a0, b1, acc[0][1], 0, 0, 0);
    acc[1][0] = __builtin_amdgcn_mfma_f32_16x16x32_bf16(a1, b0, acc[1][0], 0, 0, 0);
    acc[1][1] = __builtin_amdgcn_mfma_f32_16x16x32_bf16(a1, b1, acc[1][1], 0, 0, 0);
  }
  const int lr = (q >> 1) * 32 + ((lane >> 4) << 2);
  const int lc = (q & 1) * 32 + (lane & 15);
#pragma unroll
  for (int af = 0; af < 2; af++)
#pragma unroll
    for (int bq = 0; bq < 2; bq++)
#pragma unroll
      for (int i = 0; i < 4; i++)
        tl[kg][lr + af * 16 + i][lc + bq * 16] = acc[af][bq][i];
  __syncthreads();
  if (tid >= 512) return;
  const int r = tid >> 3;
  const int jo = (tid & 7) * 2;
  const int row = mh * 64 + r;
  const int jbase = Jb * 16 + jo;
  const float rden = __builtin_amdgcn_rcpf(Zpart[2 * row] + Zpart[2 * row + 1]);
  const size_t pb = (size_t)row * 5120;
#pragma unroll
  for (int u = 0; u < 2; u++) {
    const int jj = jbase + u;
    const int cc = jo + u;
    float ir_ = (tl[0][r][cc]      + tl[1][r][cc])      * rden + tl[2][r][cc]      + gru_b_ih[jj];
    float iz_ = (tl[0][r][16 + cc] + tl[1][r][16 + cc]) * rden + tl[2][r][16 + cc] + gru_b_ih[1024 + jj];
    float in_ = (tl[0][r][32 + cc] + tl[1][r][32 + cc]) * rden + tl[2][r][32 + cc] + gru_b_ih[2048 + jj];
    float pr_ = (tl[0][r][48 + cc] + tl[1][r][48 + cc]) * rden + tl[2][r][48 + cc];
    float hr = PS0[pb + 2048 + jj] + PS1[pb + 2048 + jj] + gru_b_hh[jj];
    float hz = PS0[pb + 3072 + jj] + PS1[pb + 3072 + jj] + gru_b_hh[1024 + jj];
    float hn = PS0[pb + 4096 + jj] + PS1[pb + 4096 + jj] + gru_b_hh[2048 + jj];
    float rg = fast_sigmoid(ir_ + hr);
    float zg = fast_sigmoid(iz_ + hz);
    float ng = fast_tanh(in_ + rg * hn);
    size_t sp = packOffN(row, jj, 32);
    float sv = s_f32p[sp];
    float sn = (1.f - zg) * ng + zg * sv;
    s_f32p[sp] = sn;
    s_b16p[sp] = (bf16)sn;
    gcpR[(size_t)row * 1024 + jj] = pr_;
  }
}

// final output for step 127 (grid 128)
__global__ __launch_bounds__(256) void kOutFinal(
    const float* __restrict__ PS0, const float* __restrict__ PS1,
    const float* __restrict__ gcpR, const float* __restrict__ bsum,
    float* __restrict__ out, bf16* __restrict__ xcatp) {
  __shared__ float smred[4];
  outPhase256(blockIdx.x, 127, PS0, PS1, gcpR, bsum, out, xcatp, smred);
}

// ---------------------------------------------------------------------------
extern "C" void kernel_launch(void* const* d_in, const int* in_sizes, int n_in,
                              void* d_out, int out_size, void* d_ws, size_t ws_size,
                              hipStream_t stream) {
  const float* h        = (const float*)d_in[0];
  const float* w_h_a    = (const float*)d_in[1];
  const float* w_s_a    = (const float*)d_in[2];
  const float* b_s_a    = (const float*)d_in[3];
  const float* w_a      = (const float*)d_in[4];
  const float* w_init_s = (const float*)d_in[5];
  const float* b_init_s = (const float*)d_in[6];
  const float* gru_w_ih = (const float*)d_in[7];
  const float* gru_w_hh = (const float*)d_in[8];
  const float* gru_b_ih = (const float*)d_in[9];
  const float* gru_b_hh = (const float*)d_in[10];
  const float* rnn_w_ih = (const float*)d_in[11];
  const float* rnn_w_hh = (const float*)d_in[12];
  const float* rnn_b_ih = (const float*)d_in[13];
  const float* rnn_b_hh = (const float*)d_in[14];
  (void)in_sizes; (void)n_in; (void)out_size; (void)ws_size;

  char* p = (char*)d_ws;
  auto alloc = [&](size_t bytes) { char* r = p; p += (bytes + 255) & ~(size_t)255; return r; };
  bf16* hbig   = (bf16*)alloc(33554432ull * 2);   // packed h (setup), then linear bf16 h
  bf16* Eb     = (bf16*)alloc(33554432ull * 2);   // exp(2 * h@w_h_a^T), linear
  bf16* h0p    = (bf16*)alloc(131072ull * 2);     // packed h[:,0,:]
  bf16* wbha_p = (bf16*)alloc(1048576ull * 2);
  bf16* wbini_p= (bf16*)alloc(1048576ull * 2);
  bf16* Wbigp  = (bf16*)alloc(8388608ull * 2);    // gate-interleaved [gih | rih_c/rhh], K=2048
  bf16* WP5p   = (bf16*)alloc(5242880ull * 2);    // [rnn_w_ih[:,1024:]; w_s_a; gru_w_hh]
  bf16* xcatp  = (bf16*)alloc(393216ull * 2);     // [c0 | c1 | y] packed, K=3072
  float* PS0   = (float*)alloc(128ull * 5120 * 4);
  float* PS1   = (float*)alloc(128ull * 5120 * 4);
  float* gcpR  = (float*)alloc(128ull * 1024 * 4);  // rnn-pre (c+y parts)
  float* s_f32p= (float*)alloc(131072ull * 4);
  bf16* s_b16p = (bf16*)alloc(131072ull * 2);
  float* Zpart = (float*)alloc(256ull * 4);
  float* bsum  = (float*)alloc(1024ull * 4);
  float* wsum  = (float*)alloc(256);
  float* out = (float*)d_out;

  // ---- setup ----
  kPackG<<<dim3(16384), 256, 0, stream>>>(h, 1024, hbig, 4194304, 0);       // h packed
  kPackG<<<dim3(64),    256, 0, stream>>>(h, 262144, h0p, 16384, 0);        // h[:,0,:]
  kPackG<<<dim3(512),   256, 0, stream>>>(w_h_a, 1024, wbha_p, 131072, 0);
  kPackG<<<dim3(512),   256, 0, stream>>>(w_init_s, 1024, wbini_p, 131072, 0);
  kPackW<<<dim3(4096),  256, 0, stream>>>(gru_w_ih, rnn_w_ih, rnn_w_hh, Wbigp);
  kPackG<<<dim3(512),   256, 0, stream>>>(rnn_w_ih + 1024, 2048, WP5p, 131072, 0);
  kPackG<<<dim3(512),   256, 0, stream>>>(w_s_a, 1024, WP5p, 131072, 1024);
  kPackG<<<dim3(1536),  256, 0, stream>>>(gru_w_hh, 1024, WP5p, 393216, 2048);
  kPrep<<<dim3(65), 256, 0, stream>>>(rnn_b_ih, rnn_b_hh, w_a, bsum, wsum, xcatp);

  kGemmE<<<dim3(8192), 256, 0, stream>>>(hbig, wbha_p, Eb);
  kCast4<<<dim3(32768), 256, 0, stream>>>(h, hbig, 8388608);   // hbig -> linear bf16 h
  kGemmS0<<<dim3(32), 256, 0, stream>>>(h0p, wbini_p, b_init_s, s_f32p, s_b16p);
  kGemmPS<<<dim3(320), 256, 0, stream>>>(s_b16p, WP5p, PS0, PS1);

  // ---- 128 sequential decode steps, 3 launches each ----
  for (int step = 0; step < 128; step++) {
    kFused1<<<dim3(384), 256, 0, stream>>>(PS0, PS1, b_s_a, w_a, wsum, Eb, hbig,
                                           gcpR, bsum, Zpart, out, xcatp, step);
    kXGru<<<dim3(128), 768, 0, stream>>>(xcatp, Wbigp, PS0, PS1,
                                         gru_b_ih, gru_b_hh, Zpart,
                                         s_f32p, s_b16p, gcpR);
    kGemmPS<<<dim3(320), 256, 0, stream>>>(s_b16p, WP5p, PS0, PS1);
  }
  kOutFinal<<<dim3(128), 256, 0, stream>>>(PS0, PS1, gcpR, bsum, out, xcatp);
}